// Round 12
// baseline (148.231 us; speedup 1.0000x reference)
//
#include <hip/hip_runtime.h>
#include <hip/hip_bf16.h>

typedef short bf16x8 __attribute__((ext_vector_type(8)));
typedef short bf16x4 __attribute__((ext_vector_type(4)));
typedef float f32x4 __attribute__((ext_vector_type(4)));

#define T_DIM 2048
#define D_DIM 64
#define WIN 128
#define QBLK 64
#define ACCT 17          // max live 16-wide k-tiles per 16-row wave tile
#define NEGBIG -1e30f

__device__ __forceinline__ short f2b(float x) {
  __hip_bfloat16 h = __float2bfloat16(x);
  return *reinterpret_cast<short*>(&h);
}
__device__ __forceinline__ bf16x8 cvt8(f32x4 a, f32x4 b) {
  bf16x8 r;
  r[0] = f2b(a[0]); r[1] = f2b(a[1]); r[2] = f2b(a[2]); r[3] = f2b(a[3]);
  r[4] = f2b(b[0]); r[5] = f2b(b[1]); r[6] = f2b(b[2]); r[7] = f2b(b[3]);
  return r;
}
// swizzled byte address in a 640B-row LDS tile
__device__ __forceinline__ int swz(int row, int b) { return row * 640 + (b ^ ((row & 7) << 4)); }

// K=16 bf16 MFMA: A-frag = 4 bf16 (m=lane&15, k=4*(lane>>4)+j) — matches
// swapped-QK^T acc layout exactly, so P never leaves registers.
#if __has_builtin(__builtin_amdgcn_mfma_f32_16x16x16bf16_1k)
__device__ __forceinline__ f32x4 mfma16(bf16x4 a, bf16x4 b, f32x4 c) {
  return __builtin_amdgcn_mfma_f32_16x16x16bf16_1k(a, b, c, 0, 0, 0);
}
#else
__device__ __forceinline__ f32x4 mfma16(bf16x4 a, bf16x4 b, f32x4 c) {
  // s_nop guards VALU-write -> MFMA-read hazard (compiler can't see through asm)
  asm volatile("s_nop 1\n\tv_mfma_f32_16x16x16_bf16 %0, %1, %2, %0"
               : "+v"(c) : "v"(a), "v"(b));
  return c;
}
#endif

__global__ __launch_bounds__(256, 4) void lsa_one(
    const float* __restrict__ Qg, const float* __restrict__ Kg,
    const float* __restrict__ Vg, float* __restrict__ Og,
    float* __restrict__ Ag) {
  const int tid = threadIdx.x;
  // XCD-chunked swizzle: XCD x hosts works [128x,128x+128) = 4 bh, 32 q-blocks
  const int work = ((blockIdx.x & 7) << 7) + (blockIdx.x >> 3);
  const int bh = work >> 5;
  const int q0 = (work & 31) * QBLK;
  int kstart = q0 - WIN; if (kstart < 0) kstart = 0;
  int kend = q0 + QBLK + WIN; if (kend > T_DIM) kend = T_DIM;
  const int KW = kend - kstart;   // 192/256/320
  const int nkt = KW >> 4;

  const float* qptr = Qg + (size_t)bh * (T_DIM * D_DIM);
  const float* kptr = Kg + (size_t)bh * (T_DIM * D_DIM);
  const float* vptr = Vg + (size_t)bh * (T_DIM * D_DIM);
  float* optr = Og + (size_t)bh * (T_DIM * D_DIM);
  float* aptr = Ag + (size_t)bh * ((size_t)T_DIM * T_DIM);

  // LDS: Vt only, 40KB -> 4 blocks/CU
  __shared__ __align__(16) char Vb[D_DIM * 640];

  // ---- stage V transposed: Vt[d][k] bf16 (consumed after the only barrier) ----
  for (int idx = tid; idx < KW * 16; idx += 256) {
    const int r = idx >> 4, c4 = idx & 15;
    f32x4 f = *(const f32x4*)(vptr + (size_t)(kstart + r) * D_DIM + c4 * 4);
    const int d0 = c4 * 4;
    *(short*)(Vb + swz(d0 + 0, r * 2)) = f2b(f[0]);
    *(short*)(Vb + swz(d0 + 1, r * 2)) = f2b(f[1]);
    *(short*)(Vb + swz(d0 + 2, r * 2)) = f2b(f[2]);
    *(short*)(Vb + swz(d0 + 3, r * 2)) = f2b(f[3]);
  }

  const int lane = tid & 63, w = tid >> 6, c = lane & 15, hi = lane >> 4;

  // Q B-frag (swapped QK^T): lane holds Q row q0+w*16+c, d-slices
  const float* qrow = qptr + (size_t)(q0 + w * 16 + c) * D_DIM + 8 * hi;
  const bf16x8 qb0 = cvt8(*(const f32x4*)qrow, *(const f32x4*)(qrow + 4));
  const bf16x8 qb1 = cvt8(*(const f32x4*)(qrow + 32), *(const f32x4*)(qrow + 36));

  // per-wave live tile range
  int klo = q0 + w * 16 - WIN - kstart; if (klo < 0) klo = 0;
  const int kt0 = klo >> 4;
  int kt1 = (q0 + w * 16 + 15 + WIN + 1 - kstart + 15) >> 4; if (kt1 > nkt) kt1 = nkt;
  const int nlive = kt1 - kt0;

  // ---- S^T = K Q^T over live tiles: acc[i][j] = S[q=c][k=16(kt0+i)+4hi+j] ----
  f32x4 acc[ACCT];
#pragma unroll
  for (int i = 0; i < ACCT; ++i) {
    acc[i] = (f32x4){0.f, 0.f, 0.f, 0.f};
    if (i < nlive) {
      const float* kr = kptr + (size_t)(kstart + (kt0 + i) * 16 + c) * D_DIM + 8 * hi;
      const bf16x8 b0 = cvt8(*(const f32x4*)kr, *(const f32x4*)(kr + 4));
      const bf16x8 b1 = cvt8(*(const f32x4*)(kr + 32), *(const f32x4*)(kr + 36));
      acc[i] = __builtin_amdgcn_mfma_f32_16x16x32_bf16(b0, qb0, acc[i], 0, 0, 0);
      acc[i] = __builtin_amdgcn_mfma_f32_16x16x32_bf16(b1, qb1, acc[i], 0, 0, 0);
    }
  }

  // ---- early zero sweep: out-of-band columns, zero data deps ----
  {
    const f32x4 zv = {0.f, 0.f, 0.f, 0.f};
    for (int rr = 0; rr < 16; ++rr) {
      float* dst = aptr + (size_t)(q0 + w * 16 + rr) * T_DIM;
      for (int col = lane * 4; col < kstart; col += 256)
        __builtin_nontemporal_store(zv, (f32x4*)(dst + col));
      for (int col = kend + lane * 4; col < T_DIM; col += 256)
        __builtin_nontemporal_store(zv, (f32x4*)(dst + col));
    }
  }

  // ---- softmax: in-lane over 68 values, 2 shfls across hi-groups ----
  const int qr = q0 + w * 16 + c;            // this lane's q-row
  const int kb = kstart + 4 * hi;
  float m = NEGBIG;
#pragma unroll
  for (int i = 0; i < ACCT; ++i)
    if (i < nlive) {
#pragma unroll
      for (int j = 0; j < 4; ++j) {
        float s = acc[i][j] * 0.125f;        // 1/sqrt(64)
        const int kcol = kb + (kt0 + i) * 16 + j;
        int dist = qr - kcol; dist = dist < 0 ? -dist : dist;
        s = (dist <= WIN) ? s : NEGBIG;
        acc[i][j] = s;
        m = fmaxf(m, s);
      }
    }
  m = fmaxf(m, __shfl_xor(m, 16));
  m = fmaxf(m, __shfl_xor(m, 32));
  float sum = 0.f;
#pragma unroll
  for (int i = 0; i < ACCT; ++i)
    if (i < nlive) {
#pragma unroll
      for (int j = 0; j < 4; ++j) {
        const float p = __expf(acc[i][j] - m);   // raw exp; normalize at stores
        acc[i][j] = p;
        sum += p;
      }
    }
  sum += __shfl_xor(sum, 16);
  sum += __shfl_xor(sum, 32);
  const float inv = 1.f / sum;

  // ---- band stores straight from acc (fp32, nt): lane owns row c, cols 16t+4hi ----
  {
    float* brow = aptr + (size_t)(q0 + w * 16 + c) * T_DIM + kstart + 4 * hi;
#pragma unroll
    for (int i = 0; i < ACCT; ++i)
      if (i < nlive) {
        f32x4 v;
#pragma unroll
        for (int j = 0; j < 4; ++j) v[j] = acc[i][j] * inv;
        __builtin_nontemporal_store(v, (f32x4*)(brow + 16 * (kt0 + i)));
      }
    const f32x4 zv = {0.f, 0.f, 0.f, 0.f};
    for (int t = 0; t < kt0; ++t)
      __builtin_nontemporal_store(zv, (f32x4*)(brow + 16 * t));
    for (int t = kt1; t < nkt; ++t)
      __builtin_nontemporal_store(zv, (f32x4*)(brow + 16 * t));
  }

  __syncthreads();   // only barrier: Vt ready for PV

  // ---- O = P V via K=16 MFMA: P A-frag direct from acc registers ----
  f32x4 ov[4];
#pragma unroll
  for (int dt = 0; dt < 4; ++dt) ov[dt] = (f32x4){0.f, 0.f, 0.f, 0.f};
#pragma unroll
  for (int i = 0; i < ACCT; ++i)
    if (i < nlive) {
      bf16x4 pa;
#pragma unroll
      for (int j = 0; j < 4; ++j) pa[j] = f2b(acc[i][j]);
      const int kb2 = (16 * (kt0 + i) + 4 * hi) * 2;
#pragma unroll
      for (int dt = 0; dt < 4; ++dt) {
        const bf16x4 vb = *(const bf16x4*)(Vb + swz(dt * 16 + c, kb2));
        ov[dt] = mfma16(pa, vb, ov[dt]);
      }
    }
  asm volatile("s_nop 7\n\ts_nop 7" :::);   // MFMA->VALU read guard (asm path)

  // ---- O scale by row-norm (q = 4hi+j lives at lane 4hi+j) + store ----
  float invq[4];
#pragma unroll
  for (int j = 0; j < 4; ++j) invq[j] = __shfl(inv, 4 * hi + j);
#pragma unroll
  for (int dt = 0; dt < 4; ++dt)
#pragma unroll
    for (int j = 0; j < 4; ++j)
      __builtin_nontemporal_store(
          ov[dt][j] * invq[j],
          optr + (size_t)(q0 + w * 16 + 4 * hi + j) * D_DIM + dt * 16 + c);
}

extern "C" void kernel_launch(void* const* d_in, const int* in_sizes, int n_in,
                              void* d_out, int out_size, void* d_ws, size_t ws_size,
                              hipStream_t stream) {
  const float* q = (const float*)d_in[0];
  const float* k = (const float*)d_in[1];
  const float* v = (const float*)d_in[2];
  float* out = (float*)d_out;
  float* attn = out + (size_t)2 * 16 * T_DIM * D_DIM;  // output first, then attn
  lsa_one<<<dim3(2 * 16 * (T_DIM / QBLK)), dim3(256), 0, stream>>>(q, k, v, out, attn);
}